// Round 8
// baseline (55.266 us; speedup 1.0000x reference)
//
#include <hip/hip_runtime.h>

// LinearAutoDecoder: rgb[n, j] = dot(X[n, 0:63],  W_pos[3*cid[n]+j, :]) +
//                                dot(X[n, 63:127], W_feat[3*cid[n]+j, :])
//
// Half-wave (32 lanes) per point, natural order (X coalesced). Lane l32
// covers features {l32, 32+l32, 64+l32, 96+l32}; boundary specials
// (feature 63 -> Wf[r][0], feature 127 -> 0) are folded into a packed table
// Wq[c][l32][12] (48B/lane, 16B-aligned) built once per launch in d_ws.
//
// 2-deep software pipeline, ping-pong banks (A = even t, B = odd t):
//   - cid loaded 2 iterations ahead,
//   - X (4 dwords) + Wq (3 float4) loaded 1 full iteration ahead,
//   - compute waits only on loads issued a full body earlier (vmcnt != 0).
// Reduction = 5-level DPP per 32-lane half (results in lanes 31/63).

constexpr int ROWW = 127;   // 63 pos + 64 latent
constexpr int NC   = 256;   // clusters

template <int CTRL, int RMASK, int BMASK>
__device__ __forceinline__ float dpp_add(float x) {
    int t = __builtin_amdgcn_update_dpp(0, __builtin_bit_cast(int, x),
                                        CTRL, RMASK, BMASK, false);
    return x + __builtin_bit_cast(float, t);
}

// Sum within each 32-lane half; valid in lane 31 (lanes 0-31) and 63 (32-63).
__device__ __forceinline__ float half_sum(float x) {
    x = dpp_add<0xB1,  0xF, 0xF>(x);  // quad_perm xor1
    x = dpp_add<0x4E,  0xF, 0xF>(x);  // quad_perm xor2
    x = dpp_add<0x114, 0xF, 0xE>(x);  // row_shr:4
    x = dpp_add<0x118, 0xF, 0xC>(x);  // row_shr:8
    x = dpp_add<0x142, 0xA, 0xF>(x);  // row_bcast:15
    return x;
}

__device__ __forceinline__ float wave_sum63(float x) {
    x = half_sum(x);
    x = dpp_add<0x143, 0xC, 0xF>(x);  // row_bcast:31
    return x;
}

// ---------------- weight pack: Wq[c][l32][12], stride 48B ----------------
// k=0: Wp[r][l32]
// k=1: l32<31 -> Wp[r][32+l32] ; l32==31 -> Wf[r][0]   (feature 63)
// k=2: Wf[r][1+l32]
// k=3: l32<31 -> Wf[r][33+l32] ; l32==31 -> 0          (feature 127, dead)
__global__ __launch_bounds__(256) void k_pack(const float* __restrict__ Wp,
                                              const float* __restrict__ Wf,
                                              float* __restrict__ Wq) {
    const int t    = threadIdx.x;
    const int c    = blockIdx.x * 8 + (t >> 5);
    const int l32  = t & 31;
    const bool edge = (l32 == 31);
    float* dst = Wq + (size_t)(c * 32 + l32) * 12;
    #pragma unroll
    for (int j = 0; j < 3; ++j) {
        const size_t r = (size_t)(3 * c + j);
        const float* wp = Wp + r * 63;
        const float* wf = Wf + r * 64;
        dst[j * 4 + 0] = wp[l32];
        dst[j * 4 + 1] = edge ? wf[0] : wp[32 + l32];
        dst[j * 4 + 2] = wf[1 + l32];
        dst[j * 4 + 3] = edge ? 0.0f : wf[33 + l32];
    }
}

// ---------------- main compute ----------------

__device__ __forceinline__ void load_x(const float* __restrict__ X, int p,
                                       int l32, int o3,
                                       float& x0, float& x1, float& x2, float& x3) {
    const float* xr = X + (size_t)p * ROWW;
    x0 = xr[l32]; x1 = xr[32 + l32]; x2 = xr[64 + l32]; x3 = xr[o3];
}

__device__ __forceinline__ void load_w(const float* __restrict__ Wq, int c, int l32,
                                       float4& w0, float4& w1, float4& w2) {
    const float4* wr = (const float4*)(Wq + (size_t)((c << 5) + l32) * 12);
    w0 = wr[0]; w1 = wr[1]; w2 = wr[2];
}

__device__ __forceinline__ void compute_pt(float x0, float x1, float x2, float x3,
                                           const float4& w0, const float4& w1,
                                           const float4& w2,
                                           float* __restrict__ out, int p, bool edge) {
    float a0 = fmaf(x0, w0.x, fmaf(x1, w0.y, fmaf(x2, w0.z, x3 * w0.w)));
    float a1 = fmaf(x0, w1.x, fmaf(x1, w1.y, fmaf(x2, w1.z, x3 * w1.w)));
    float a2 = fmaf(x0, w2.x, fmaf(x1, w2.y, fmaf(x2, w2.z, x3 * w2.w)));
    a0 = half_sum(a0);
    a1 = half_sum(a1);
    a2 = half_sum(a2);
    if (edge) {                       // lanes 31 and 63: own half's point
        float* o = out + 3 * (size_t)p;
        o[0] = a0; o[1] = a1; o[2] = a2;
    }
}

__global__ __launch_bounds__(256, 8) void k_main(
    const float* __restrict__ X,
    const int*   __restrict__ cid,
    const float* __restrict__ Wq,   // [256][32][12]
    float*       __restrict__ out,  // [N][3]
    int npts)
{
    const int lane = threadIdx.x & 63;
    const int l32  = lane & 31;
    const int half = lane >> 5;
    const bool edge = (l32 == 31);
    const int o3   = edge ? 126 : 96 + l32;   // dead feature 127 clamped (w=0)
    const int wid  = (blockIdx.x * blockDim.x + threadIdx.x) >> 6;
    const int nW   = (gridDim.x * blockDim.x) >> 6;
    const int npairs = (npts + 1) >> 1;

    if (wid >= npairs) return;                // wave-uniform
    const int niter = (npairs - 1 - wid) / nW + 1;

    // pair index for iteration t, clamped (beyond-range prefetch is benign)
    auto pidx = [&](int t) -> int {
        int g = wid + t * nW;
        if (g > npairs - 1) g = npairs - 1;
        int p = 2 * g + half;
        return (p < npts) ? p : (npts - 1);
    };

    // ---- prologue: fill banks A (t=0) and B (t=1), cid for t=2,3 ----
    int pA = pidx(0), pB = pidx(1);
    int cA = cid[pA];
    int cB = cid[pB];
    float xA0, xA1, xA2, xA3, xB0, xB1, xB2, xB3;
    float4 wA0, wA1, wA2, wB0, wB1, wB2;
    load_x(X, pA, l32, o3, xA0, xA1, xA2, xA3);
    load_x(X, pB, l32, o3, xB0, xB1, xB2, xB3);
    load_w(Wq, cA, l32, wA0, wA1, wA2);       // waits on cA (prologue only)
    load_w(Wq, cB, l32, wB0, wB1, wB2);
    int cNA = cid[pidx(2)];                   // cluster for t+2 (A bank)
    int cNB = cid[pidx(3)];                   // cluster for t+3 (B bank)

    int t = 0;
    while (t + 2 <= niter) {
        // ---- A-body: compute t, then prefetch t+2 into bank A ----
        compute_pt(xA0, xA1, xA2, xA3, wA0, wA1, wA2, out, pA, edge);
        pA = pidx(t + 2);
        load_x(X, pA, l32, o3, xA0, xA1, xA2, xA3);
        load_w(Wq, cNA, l32, wA0, wA1, wA2);  // cNA issued a body ago
        cNA = cid[pidx(t + 4)];               // cid 2 iterations ahead

        // ---- B-body: compute t+1, then prefetch t+3 into bank B ----
        compute_pt(xB0, xB1, xB2, xB3, wB0, wB1, wB2, out, pB, edge);
        pB = pidx(t + 3);
        load_x(X, pB, l32, o3, xB0, xB1, xB2, xB3);
        load_w(Wq, cNB, l32, wB0, wB1, wB2);
        cNB = cid[pidx(t + 5)];

        t += 2;
    }
    if (t < niter)   // odd tail: iteration t is even -> bank A
        compute_pt(xA0, xA1, xA2, xA3, wA0, wA1, wA2, out, pA, edge);
}

// ---------------- fallback (ws too small): round-3 direct kernel ----------------

__global__ __launch_bounds__(256, 8) void lad_fallback(
    const float* __restrict__ X, const int* __restrict__ cid,
    const float* __restrict__ Wp, const float* __restrict__ Wf,
    float* __restrict__ out, int npts)
{
    const int lane  = threadIdx.x & 63;
    const int wid   = (blockIdx.x * blockDim.x + threadIdx.x) >> 6;
    const int nW    = (gridDim.x * blockDim.x) >> 6;
    const int lanec = (lane < 63) ? lane : 62;
    const bool l63  = (lane == 63);

    for (int n = wid; n < npts; n += 2 * nW) {
        const int n2 = n + nW;
        const bool has2 = (n2 < npts);

        const float* x0 = X + (size_t)n * ROWW;
        float xa0 = x0[lane];
        float xb0 = x0[63 + lane];
        int   c0  = __builtin_amdgcn_readfirstlane(cid[n]);

        float xa1 = 0.0f, xb1 = 0.0f;
        int   c1  = 0;
        if (has2) {
            const float* x1 = X + (size_t)n2 * ROWW;
            xa1 = x1[lane];
            xb1 = x1[63 + lane];
            c1  = __builtin_amdgcn_readfirstlane(cid[n2]);
        }
        if (l63) { xa0 = 0.0f; xa1 = 0.0f; }

        const float* wp0 = Wp + (size_t)(3 * c0) * 63;
        const float* wf0 = Wf + (size_t)(3 * c0) * 64;
        const float* wp1 = Wp + (size_t)(3 * c1) * 63;
        const float* wf1 = Wf + (size_t)(3 * c1) * 64;

        float a00 = fmaf(xa0, wp0[lanec],       xb0 * wf0[lane]);
        float a01 = fmaf(xa0, wp0[63 + lanec],  xb0 * wf0[64 + lane]);
        float a02 = fmaf(xa0, wp0[126 + lanec], xb0 * wf0[128 + lane]);
        float a10 = fmaf(xa1, wp1[lanec],       xb1 * wf1[lane]);
        float a11 = fmaf(xa1, wp1[63 + lanec],  xb1 * wf1[64 + lane]);
        float a12 = fmaf(xa1, wp1[126 + lanec], xb1 * wf1[128 + lane]);

        a00 = wave_sum63(a00); a01 = wave_sum63(a01); a02 = wave_sum63(a02);
        a10 = wave_sum63(a10); a11 = wave_sum63(a11); a12 = wave_sum63(a12);

        if (l63) {
            float* o0 = out + 3 * (size_t)n;
            o0[0] = a00; o0[1] = a01; o0[2] = a02;
            if (has2) {
                float* o1 = out + 3 * (size_t)n2;
                o1[0] = a10; o1[1] = a11; o1[2] = a12;
            }
        }
    }
}

extern "C" void kernel_launch(void* const* d_in, const int* in_sizes, int n_in,
                              void* d_out, int out_size, void* d_ws, size_t ws_size,
                              hipStream_t stream) {
    const float* X   = (const float*)d_in[0];
    const int*   cid = (const int*)d_in[1];
    const float* Wp  = (const float*)d_in[2];
    const float* Wf  = (const float*)d_in[3];
    float* out = (float*)d_out;
    const int npts = in_sizes[1];   // cluster_ids element count == N

    const size_t wq_bytes = (size_t)NC * 32 * 12 * sizeof(float);  // 384 KiB
    if (ws_size < wq_bytes) {
        dim3 grid(2048), block(256);
        hipLaunchKernelGGL(lad_fallback, grid, block, 0, stream,
                           X, cid, Wp, Wf, out, npts);
        return;
    }

    float* Wq = (float*)d_ws;
    hipLaunchKernelGGL(k_pack, dim3(NC / 8), dim3(256), 0, stream, Wp, Wf, Wq);
    hipLaunchKernelGGL(k_main, dim3(2048),   dim3(256), 0, stream,
                       X, cid, Wq, out, npts);
}

// Round 9
// 38.573 us; speedup vs baseline: 1.4327x; 1.4327x over previous
//
#include <hip/hip_runtime.h>

// LinearAutoDecoder: rgb[n, j] = dot(X[n, 0:63],  W_pos[3*cid[n]+j, :]) +
//                                dot(X[n, 63:127], W_feat[3*cid[n]+j, :])
//
// Quarter-wave (16 lanes) per point, 4 points per wave-iteration.
// Lane l16 covers features f = 16k + l16 (k=0..7). Weights come from a
// packed table Wt[c][6][16] float4 built once in d_ws:
//   chunk cc = j*2 + h holds, for lane l16, component m: weight of feature
//   f = 16*(4h+m) + l16 for output j  (f==63 -> Wf[r][0], f==127 -> 0).
// A quarter's 6 float4 loads are each 256B contiguous (cluster-uniform).
// cid is prefetched one iteration ahead (breaks cid->w chain).
// Reduction: 4 DPP levels within each 16-lane row; sums land in lanes
// 15/31/47/63 which store their point's 3 outputs.

constexpr int ROWW = 127;   // 63 pos + 64 latent
constexpr int NC   = 256;   // clusters

template <int CTRL, int RMASK, int BMASK>
__device__ __forceinline__ float dpp_add(float x) {
    int t = __builtin_amdgcn_update_dpp(0, __builtin_bit_cast(int, x),
                                        CTRL, RMASK, BMASK, false);
    return x + __builtin_bit_cast(float, t);
}

// Sum within each 16-lane row; valid in lanes 15, 31, 47, 63.
__device__ __forceinline__ float row_sum(float x) {
    x = dpp_add<0xB1,  0xF, 0xF>(x);  // quad_perm xor1
    x = dpp_add<0x4E,  0xF, 0xF>(x);  // quad_perm xor2
    x = dpp_add<0x114, 0xF, 0xE>(x);  // row_shr:4
    x = dpp_add<0x118, 0xF, 0xC>(x);  // row_shr:8
    return x;
}

// Full-wave sum for the fallback kernel; valid in lane 63.
__device__ __forceinline__ float wave_sum63(float x) {
    x = row_sum(x);
    x = dpp_add<0x142, 0xA, 0xF>(x);  // row_bcast:15
    x = dpp_add<0x143, 0xC, 0xF>(x);  // row_bcast:31
    return x;
}

// ---------------- weight pack: Wt[c][6][16] float4 ----------------

__device__ __forceinline__ float wval(const float* Wp, const float* Wf,
                                      int r, int f) {
    if (f < 63)  return Wp[(size_t)r * 63 + f];
    if (f == 63) return Wf[(size_t)r * 64];
    if (f < 127) return Wf[(size_t)r * 64 + (f - 63)];
    return 0.0f;   // dead feature 127
}

__global__ __launch_bounds__(256) void k_pack(const float* __restrict__ Wp,
                                              const float* __restrict__ Wf,
                                              float4* __restrict__ Wt) {
    const int c   = blockIdx.x * 16 + (threadIdx.x >> 4);
    const int l16 = threadIdx.x & 15;
    #pragma unroll
    for (int j = 0; j < 3; ++j) {
        const int r = 3 * c + j;
        #pragma unroll
        for (int h = 0; h < 2; ++h) {
            float4 v;
            v.x = wval(Wp, Wf, r, 16 * (4 * h + 0) + l16);
            v.y = wval(Wp, Wf, r, 16 * (4 * h + 1) + l16);
            v.z = wval(Wp, Wf, r, 16 * (4 * h + 2) + l16);
            v.w = wval(Wp, Wf, r, 16 * (4 * h + 3) + l16);
            Wt[(size_t)(c * 6 + j * 2 + h) * 16 + l16] = v;
        }
    }
}

// ---------------- main compute ----------------

__global__ __launch_bounds__(256, 8) void k_main(
    const float*  __restrict__ X,
    const int*    __restrict__ cid,
    const float4* __restrict__ Wt,   // [256][6][16]
    float*        __restrict__ out,  // [N][3]
    int npts)
{
    const int lane = threadIdx.x & 63;
    const int l16  = lane & 15;
    const int qr   = lane >> 4;                 // quarter id 0..3
    const bool leader = (l16 == 15);
    const int o7   = leader ? 126 : 112 + l16;  // clamp dead feature 127
    const int wid  = (blockIdx.x * blockDim.x + threadIdx.x) >> 6;
    const int nW   = (gridDim.x * blockDim.x) >> 6;
    const int step = nW * 4;                    // points per global iteration
    const int last = npts - 1;
    const int niter = (npts + step - 1) / step;

    int p = wid * 4 + qr;
    int c = cid[min(p, last)];

    for (int t = 0; t < niter; ++t) {
        const int pc = min(p, last);

        // ---- X loads first (HBM latency, covered by TLP) ----
        const float* xr = X + (size_t)pc * ROWW;
        const float x0 = xr[l16];
        const float x1 = xr[16 + l16];
        const float x2 = xr[32 + l16];
        const float x3 = xr[48 + l16];
        const float x4 = xr[64 + l16];
        const float x5 = xr[80 + l16];
        const float x6 = xr[96 + l16];
        const float x7 = xr[o7];

        // ---- prefetch next iteration's cid ----
        const int pn = p + step;
        const int cn = cid[min(pn, last)];

        // ---- weights: 6 x 256B-contiguous float4 loads (c from prev iter) ----
        const float4* wb = Wt + (size_t)c * 96 + l16;
        const float4 w0 = wb[0];        // j=0, k=0..3
        const float4 w1 = wb[16];       // j=0, k=4..7
        const float4 w2 = wb[32];       // j=1, k=0..3
        const float4 w3 = wb[48];       // j=1, k=4..7
        const float4 w4 = wb[64];       // j=2, k=0..3
        const float4 w5 = wb[80];       // j=2, k=4..7

        float a0 = fmaf(x0, w0.x, x1 * w0.y) + fmaf(x2, w0.z, x3 * w0.w)
                 + fmaf(x4, w1.x, x5 * w1.y) + fmaf(x6, w1.z, x7 * w1.w);
        float a1 = fmaf(x0, w2.x, x1 * w2.y) + fmaf(x2, w2.z, x3 * w2.w)
                 + fmaf(x4, w3.x, x5 * w3.y) + fmaf(x6, w3.z, x7 * w3.w);
        float a2 = fmaf(x0, w4.x, x1 * w4.y) + fmaf(x2, w4.z, x3 * w4.w)
                 + fmaf(x4, w5.x, x5 * w5.y) + fmaf(x6, w5.z, x7 * w5.w);

        a0 = row_sum(a0);
        a1 = row_sum(a1);
        a2 = row_sum(a2);

        if (leader && p < npts) {       // lanes 15/31/47/63: own quarter's point
            float* o = out + 3 * (size_t)p;
            o[0] = a0; o[1] = a1; o[2] = a2;
        }

        p = pn; c = cn;
    }
}

// ---------------- fallback (ws too small): round-3 direct kernel ----------------

__global__ __launch_bounds__(256, 8) void lad_fallback(
    const float* __restrict__ X, const int* __restrict__ cid,
    const float* __restrict__ Wp, const float* __restrict__ Wf,
    float* __restrict__ out, int npts)
{
    const int lane  = threadIdx.x & 63;
    const int wid   = (blockIdx.x * blockDim.x + threadIdx.x) >> 6;
    const int nW    = (gridDim.x * blockDim.x) >> 6;
    const int lanec = (lane < 63) ? lane : 62;
    const bool l63  = (lane == 63);

    for (int n = wid; n < npts; n += 2 * nW) {
        const int n2 = n + nW;
        const bool has2 = (n2 < npts);

        const float* x0 = X + (size_t)n * ROWW;
        float xa0 = x0[lane];
        float xb0 = x0[63 + lane];
        int   c0  = __builtin_amdgcn_readfirstlane(cid[n]);

        float xa1 = 0.0f, xb1 = 0.0f;
        int   c1  = 0;
        if (has2) {
            const float* x1 = X + (size_t)n2 * ROWW;
            xa1 = x1[lane];
            xb1 = x1[63 + lane];
            c1  = __builtin_amdgcn_readfirstlane(cid[n2]);
        }
        if (l63) { xa0 = 0.0f; xa1 = 0.0f; }

        const float* wp0 = Wp + (size_t)(3 * c0) * 63;
        const float* wf0 = Wf + (size_t)(3 * c0) * 64;
        const float* wp1 = Wp + (size_t)(3 * c1) * 63;
        const float* wf1 = Wf + (size_t)(3 * c1) * 64;

        float a00 = fmaf(xa0, wp0[lanec],       xb0 * wf0[lane]);
        float a01 = fmaf(xa0, wp0[63 + lanec],  xb0 * wf0[64 + lane]);
        float a02 = fmaf(xa0, wp0[126 + lanec], xb0 * wf0[128 + lane]);
        float a10 = fmaf(xa1, wp1[lanec],       xb1 * wf1[lane]);
        float a11 = fmaf(xa1, wp1[63 + lanec],  xb1 * wf1[64 + lane]);
        float a12 = fmaf(xa1, wp1[126 + lanec], xb1 * wf1[128 + lane]);

        a00 = wave_sum63(a00); a01 = wave_sum63(a01); a02 = wave_sum63(a02);
        a10 = wave_sum63(a10); a11 = wave_sum63(a11); a12 = wave_sum63(a12);

        if (l63) {
            float* o0 = out + 3 * (size_t)n;
            o0[0] = a00; o0[1] = a01; o0[2] = a02;
            if (has2) {
                float* o1 = out + 3 * (size_t)n2;
                o1[0] = a10; o1[1] = a11; o1[2] = a12;
            }
        }
    }
}

extern "C" void kernel_launch(void* const* d_in, const int* in_sizes, int n_in,
                              void* d_out, int out_size, void* d_ws, size_t ws_size,
                              hipStream_t stream) {
    const float* X   = (const float*)d_in[0];
    const int*   cid = (const int*)d_in[1];
    const float* Wp  = (const float*)d_in[2];
    const float* Wf  = (const float*)d_in[3];
    float* out = (float*)d_out;
    const int npts = in_sizes[1];   // cluster_ids element count == N

    const size_t wt_bytes = (size_t)NC * 6 * 16 * sizeof(float4);  // 384 KiB
    if (ws_size < wt_bytes) {
        dim3 grid(2048), block(256);
        hipLaunchKernelGGL(lad_fallback, grid, block, 0, stream,
                           X, cid, Wp, Wf, out, npts);
        return;
    }

    float4* Wt = (float4*)d_ws;
    hipLaunchKernelGGL(k_pack, dim3(NC / 16), dim3(256), 0, stream, Wp, Wf, Wt);
    hipLaunchKernelGGL(k_main, dim3(2048),    dim3(256), 0, stream,
                       X, cid, Wt, out, npts);
}

// Round 10
// 37.573 us; speedup vs baseline: 1.4709x; 1.0266x over previous
//
#include <hip/hip_runtime.h>

// LinearAutoDecoder: rgb[n, j] = dot(X[n, 0:63],  W_pos[3*cid[n]+j, :]) +
//                                dot(X[n, 63:127], W_feat[3*cid[n]+j, :])
//
// Quarter-wave (16 lanes) per point, 4 points per wave-iteration, with a
// 1-iteration software pipeline whose ISSUE ORDER is FIFO-wait-correct:
//   per body: [Wt loads for current]  (cid resolved one iter ago)
//             sched_barrier
//             [cid + X loads for NEXT iteration]
//             sched_barrier
//             [compute current + store]
// The FMA's s_waitcnt covers only the Wt group (vmcnt leaves next-X/cid in
// flight), so X's ~900cy HBM latency is hidden per-wave in addition to TLP.
// Lane l16 covers features f = 16k + l16 (k=0..7); boundary specials
// (f==63 -> Wf[r][0], f==127 -> 0) are folded into the packed table
// Wt[c][6][16] float4 (each quarter's float4 load = 256B contiguous).
// Reduction: 4 DPP levels in each 16-lane row -> lanes 15/31/47/63 store.

constexpr int ROWW = 127;   // 63 pos + 64 latent
constexpr int NC   = 256;   // clusters

template <int CTRL, int RMASK, int BMASK>
__device__ __forceinline__ float dpp_add(float x) {
    int t = __builtin_amdgcn_update_dpp(0, __builtin_bit_cast(int, x),
                                        CTRL, RMASK, BMASK, false);
    return x + __builtin_bit_cast(float, t);
}

// Sum within each 16-lane row; valid in lanes 15, 31, 47, 63.
__device__ __forceinline__ float row_sum(float x) {
    x = dpp_add<0xB1,  0xF, 0xF>(x);  // quad_perm xor1
    x = dpp_add<0x4E,  0xF, 0xF>(x);  // quad_perm xor2
    x = dpp_add<0x114, 0xF, 0xE>(x);  // row_shr:4
    x = dpp_add<0x118, 0xF, 0xC>(x);  // row_shr:8
    return x;
}

// Full-wave sum for the fallback kernel; valid in lane 63.
__device__ __forceinline__ float wave_sum63(float x) {
    x = row_sum(x);
    x = dpp_add<0x142, 0xA, 0xF>(x);  // row_bcast:15
    x = dpp_add<0x143, 0xC, 0xF>(x);  // row_bcast:31
    return x;
}

// ---------------- weight pack: Wt[c][6][16] float4 ----------------

__device__ __forceinline__ float wval(const float* Wp, const float* Wf,
                                      int r, int f) {
    if (f < 63)  return Wp[(size_t)r * 63 + f];
    if (f == 63) return Wf[(size_t)r * 64];
    if (f < 127) return Wf[(size_t)r * 64 + (f - 63)];
    return 0.0f;   // dead feature 127
}

__global__ __launch_bounds__(256) void k_pack(const float* __restrict__ Wp,
                                              const float* __restrict__ Wf,
                                              float4* __restrict__ Wt) {
    const int c   = blockIdx.x * 16 + (threadIdx.x >> 4);
    const int l16 = threadIdx.x & 15;
    #pragma unroll
    for (int j = 0; j < 3; ++j) {
        const int r = 3 * c + j;
        #pragma unroll
        for (int h = 0; h < 2; ++h) {
            float4 v;
            v.x = wval(Wp, Wf, r, 16 * (4 * h + 0) + l16);
            v.y = wval(Wp, Wf, r, 16 * (4 * h + 1) + l16);
            v.z = wval(Wp, Wf, r, 16 * (4 * h + 2) + l16);
            v.w = wval(Wp, Wf, r, 16 * (4 * h + 3) + l16);
            Wt[(size_t)(c * 6 + j * 2 + h) * 16 + l16] = v;
        }
    }
}

// ---------------- main compute (npts % (nW*4) == 0 specialization) --------

__global__ __launch_bounds__(256, 8) void k_main_pipe(
    const float*  __restrict__ X,
    const int*    __restrict__ cid,
    const float4* __restrict__ Wt,   // [256][6][16]
    float*        __restrict__ out,  // [N][3]
    int npts)
{
    const int lane = threadIdx.x & 63;
    const int l16  = lane & 15;
    const int qr   = lane >> 4;                 // quarter id 0..3
    const bool leader = (l16 == 15);
    const int o7   = leader ? 126 : 112 + l16;  // clamp dead feature 127
    const int wid  = (blockIdx.x * blockDim.x + threadIdx.x) >> 6;
    const int nW   = (gridDim.x * blockDim.x) >> 6;
    const int step = nW * 4;                    // points per global iteration
    const int last = npts - 1;
    const int niter = npts / step;              // exact by caller contract

    int p = wid * 4 + qr;

    // ---- prologue: cid + X for iteration 0 ----
    int c = cid[p];
    {
        const float* xr = X + (size_t)p * ROWW;
        // loads materialized below
    }
    const float* xr0 = X + (size_t)p * ROWW;
    float x0 = xr0[l16],      x1 = xr0[16 + l16];
    float x2 = xr0[32 + l16], x3 = xr0[48 + l16];
    float x4 = xr0[64 + l16], x5 = xr0[80 + l16];
    float x6 = xr0[96 + l16], x7 = xr0[o7];

    for (int t = 0; t < niter; ++t) {
        // ---- (1) weights for CURRENT point (c resolved one iter ago) ----
        const float4* wb = Wt + (size_t)c * 96 + l16;
        const float4 w0 = wb[0];        // j=0, k=0..3
        const float4 w1 = wb[16];       // j=0, k=4..7
        const float4 w2 = wb[32];       // j=1, k=0..3
        const float4 w3 = wb[48];       // j=1, k=4..7
        const float4 w4 = wb[64];       // j=2, k=0..3
        const float4 w5 = wb[80];       // j=2, k=4..7
        __builtin_amdgcn_sched_barrier(0);

        // ---- (2) prefetch NEXT iteration's cid + X ----
        int pn = p + step;
        if (pn > last) pn = last;       // benign duplicate on final prefetch
        const int cn = cid[pn];
        const float* yr = X + (size_t)pn * ROWW;
        const float y0 = yr[l16],      y1 = yr[16 + l16];
        const float y2 = yr[32 + l16], y3 = yr[48 + l16];
        const float y4 = yr[64 + l16], y5 = yr[80 + l16];
        const float y6 = yr[96 + l16], y7 = yr[o7];
        __builtin_amdgcn_sched_barrier(0);

        // ---- (3) compute current (waits only on Wt group) ----
        float a0 = fmaf(x0, w0.x, x1 * w0.y) + fmaf(x2, w0.z, x3 * w0.w)
                 + fmaf(x4, w1.x, x5 * w1.y) + fmaf(x6, w1.z, x7 * w1.w);
        float a1 = fmaf(x0, w2.x, x1 * w2.y) + fmaf(x2, w2.z, x3 * w2.w)
                 + fmaf(x4, w3.x, x5 * w3.y) + fmaf(x6, w3.z, x7 * w3.w);
        float a2 = fmaf(x0, w4.x, x1 * w4.y) + fmaf(x2, w4.z, x3 * w4.w)
                 + fmaf(x4, w5.x, x5 * w5.y) + fmaf(x6, w5.z, x7 * w5.w);

        a0 = row_sum(a0);
        a1 = row_sum(a1);
        a2 = row_sum(a2);

        if (leader) {                   // lanes 15/31/47/63: own quarter's point
            float* o = out + 3 * (size_t)p;
            o[0] = a0; o[1] = a1; o[2] = a2;
        }

        // ---- (4) rotate banks ----
        p += step; c = cn;
        x0 = y0; x1 = y1; x2 = y2; x3 = y3;
        x4 = y4; x5 = y5; x6 = y6; x7 = y7;
    }
}

// ---------------- generic quarter-wave kernel (r9, any npts) ----------------

__global__ __launch_bounds__(256, 8) void k_main(
    const float*  __restrict__ X,
    const int*    __restrict__ cid,
    const float4* __restrict__ Wt,   // [256][6][16]
    float*        __restrict__ out,  // [N][3]
    int npts)
{
    const int lane = threadIdx.x & 63;
    const int l16  = lane & 15;
    const int qr   = lane >> 4;
    const bool leader = (l16 == 15);
    const int o7   = leader ? 126 : 112 + l16;
    const int wid  = (blockIdx.x * blockDim.x + threadIdx.x) >> 6;
    const int nW   = (gridDim.x * blockDim.x) >> 6;
    const int step = nW * 4;
    const int last = npts - 1;
    const int niter = (npts + step - 1) / step;

    int p = wid * 4 + qr;
    int c = cid[min(p, last)];

    for (int t = 0; t < niter; ++t) {
        const int pc = min(p, last);
        const float* xr = X + (size_t)pc * ROWW;
        const float x0 = xr[l16];
        const float x1 = xr[16 + l16];
        const float x2 = xr[32 + l16];
        const float x3 = xr[48 + l16];
        const float x4 = xr[64 + l16];
        const float x5 = xr[80 + l16];
        const float x6 = xr[96 + l16];
        const float x7 = xr[o7];

        const int pn = p + step;
        const int cn = cid[min(pn, last)];

        const float4* wb = Wt + (size_t)c * 96 + l16;
        const float4 w0 = wb[0];
        const float4 w1 = wb[16];
        const float4 w2 = wb[32];
        const float4 w3 = wb[48];
        const float4 w4 = wb[64];
        const float4 w5 = wb[80];

        float a0 = fmaf(x0, w0.x, x1 * w0.y) + fmaf(x2, w0.z, x3 * w0.w)
                 + fmaf(x4, w1.x, x5 * w1.y) + fmaf(x6, w1.z, x7 * w1.w);
        float a1 = fmaf(x0, w2.x, x1 * w2.y) + fmaf(x2, w2.z, x3 * w2.w)
                 + fmaf(x4, w3.x, x5 * w3.y) + fmaf(x6, w3.z, x7 * w3.w);
        float a2 = fmaf(x0, w4.x, x1 * w4.y) + fmaf(x2, w4.z, x3 * w4.w)
                 + fmaf(x4, w5.x, x5 * w5.y) + fmaf(x6, w5.z, x7 * w5.w);

        a0 = row_sum(a0);
        a1 = row_sum(a1);
        a2 = row_sum(a2);

        if (leader && p < npts) {
            float* o = out + 3 * (size_t)p;
            o[0] = a0; o[1] = a1; o[2] = a2;
        }

        p = pn; c = cn;
    }
}

// ---------------- fallback (ws too small): round-3 direct kernel ----------------

__global__ __launch_bounds__(256, 8) void lad_fallback(
    const float* __restrict__ X, const int* __restrict__ cid,
    const float* __restrict__ Wp, const float* __restrict__ Wf,
    float* __restrict__ out, int npts)
{
    const int lane  = threadIdx.x & 63;
    const int wid   = (blockIdx.x * blockDim.x + threadIdx.x) >> 6;
    const int nW    = (gridDim.x * blockDim.x) >> 6;
    const int lanec = (lane < 63) ? lane : 62;
    const bool l63  = (lane == 63);

    for (int n = wid; n < npts; n += 2 * nW) {
        const int n2 = n + nW;
        const bool has2 = (n2 < npts);

        const float* x0 = X + (size_t)n * ROWW;
        float xa0 = x0[lane];
        float xb0 = x0[63 + lane];
        int   c0  = __builtin_amdgcn_readfirstlane(cid[n]);

        float xa1 = 0.0f, xb1 = 0.0f;
        int   c1  = 0;
        if (has2) {
            const float* x1 = X + (size_t)n2 * ROWW;
            xa1 = x1[lane];
            xb1 = x1[63 + lane];
            c1  = __builtin_amdgcn_readfirstlane(cid[n2]);
        }
        if (l63) { xa0 = 0.0f; xa1 = 0.0f; }

        const float* wp0 = Wp + (size_t)(3 * c0) * 63;
        const float* wf0 = Wf + (size_t)(3 * c0) * 64;
        const float* wp1 = Wp + (size_t)(3 * c1) * 63;
        const float* wf1 = Wf + (size_t)(3 * c1) * 64;

        float a00 = fmaf(xa0, wp0[lanec],       xb0 * wf0[lane]);
        float a01 = fmaf(xa0, wp0[63 + lanec],  xb0 * wf0[64 + lane]);
        float a02 = fmaf(xa0, wp0[126 + lanec], xb0 * wf0[128 + lane]);
        float a10 = fmaf(xa1, wp1[lanec],       xb1 * wf1[lane]);
        float a11 = fmaf(xa1, wp1[63 + lanec],  xb1 * wf1[64 + lane]);
        float a12 = fmaf(xa1, wp1[126 + lanec], xb1 * wf1[128 + lane]);

        a00 = wave_sum63(a00); a01 = wave_sum63(a01); a02 = wave_sum63(a02);
        a10 = wave_sum63(a10); a11 = wave_sum63(a11); a12 = wave_sum63(a12);

        if (l63) {
            float* o0 = out + 3 * (size_t)n;
            o0[0] = a00; o0[1] = a01; o0[2] = a02;
            if (has2) {
                float* o1 = out + 3 * (size_t)n2;
                o1[0] = a10; o1[1] = a11; o1[2] = a12;
            }
        }
    }
}

extern "C" void kernel_launch(void* const* d_in, const int* in_sizes, int n_in,
                              void* d_out, int out_size, void* d_ws, size_t ws_size,
                              hipStream_t stream) {
    const float* X   = (const float*)d_in[0];
    const int*   cid = (const int*)d_in[1];
    const float* Wp  = (const float*)d_in[2];
    const float* Wf  = (const float*)d_in[3];
    float* out = (float*)d_out;
    const int npts = in_sizes[1];   // cluster_ids element count == N

    const size_t wt_bytes = (size_t)NC * 6 * 16 * sizeof(float4);  // 384 KiB
    if (ws_size < wt_bytes) {
        dim3 grid(2048), block(256);
        hipLaunchKernelGGL(lad_fallback, grid, block, 0, stream,
                           X, cid, Wp, Wf, out, npts);
        return;
    }

    float4* Wt = (float4*)d_ws;
    hipLaunchKernelGGL(k_pack, dim3(NC / 16), dim3(256), 0, stream, Wp, Wf, Wt);

    const int nW = (2048 * 256) >> 6;   // 8192 waves
    const int step = nW * 4;
    if (npts % step == 0) {
        hipLaunchKernelGGL(k_main_pipe, dim3(2048), dim3(256), 0, stream,
                           X, cid, Wt, out, npts);
    } else {
        hipLaunchKernelGGL(k_main, dim3(2048), dim3(256), 0, stream,
                           X, cid, Wt, out, npts);
    }
}

// Round 11
// 32.693 us; speedup vs baseline: 1.6905x; 1.1493x over previous
//
#include <hip/hip_runtime.h>

// LinearAutoDecoder: rgb[n, j] = dot(X[n, 0:63],  W_pos[3*cid[n]+j, :]) +
//                                dot(X[n, 63:127], W_feat[3*cid[n]+j, :])
//
// Quarter-wave (16 lanes) per point, 4 points/wave-iteration, 1-iter pipe:
//   per body: [bf16 Wt loads for current] | sched_barrier |
//             [cid + X for NEXT] | sched_barrier | [unpack+FMA+DPP+store]
// Weights are a bf16-packed table Wt[c][3][16] uint4 (192 KiB) built once in
// d_ws: lane l16, output j holds 8 bf16 weights for features f=16k+l16
// (k=0..7; f==63 -> Wf[r][0], f==127 -> 0 folded in). Per-point weight
// traffic: 768 B (vs 1536 fp32) and 3 VMEM loads (vs 6) -> halves the
// L1/L2 weight stream that bound r10. Unpack = shift/and (VALU-cheap).
// Reduction: 4 DPP levels per 16-lane row -> lanes 15/31/47/63 store.

constexpr int ROWW = 127;   // 63 pos + 64 latent
constexpr int NC   = 256;   // clusters

template <int CTRL, int RMASK, int BMASK>
__device__ __forceinline__ float dpp_add(float x) {
    int t = __builtin_amdgcn_update_dpp(0, __builtin_bit_cast(int, x),
                                        CTRL, RMASK, BMASK, false);
    return x + __builtin_bit_cast(float, t);
}

// Sum within each 16-lane row; valid in lanes 15, 31, 47, 63.
__device__ __forceinline__ float row_sum(float x) {
    x = dpp_add<0xB1,  0xF, 0xF>(x);  // quad_perm xor1
    x = dpp_add<0x4E,  0xF, 0xF>(x);  // quad_perm xor2
    x = dpp_add<0x114, 0xF, 0xE>(x);  // row_shr:4
    x = dpp_add<0x118, 0xF, 0xC>(x);  // row_shr:8
    return x;
}

// Full-wave sum for the fallback kernel; valid in lane 63.
__device__ __forceinline__ float wave_sum63(float x) {
    x = row_sum(x);
    x = dpp_add<0x142, 0xA, 0xF>(x);  // row_bcast:15
    x = dpp_add<0x143, 0xC, 0xF>(x);  // row_bcast:31
    return x;
}

// bf16 helpers
__device__ __forceinline__ unsigned f2bf(float f) {      // RNE
    unsigned u = __builtin_bit_cast(unsigned, f);
    return (u + 0x7fffu + ((u >> 16) & 1u)) >> 16;
}
__device__ __forceinline__ float blo(unsigned u) {       // low bf16 -> f32
    return __builtin_bit_cast(float, u << 16);
}
__device__ __forceinline__ float bhi(unsigned u) {       // high bf16 -> f32
    return __builtin_bit_cast(float, u & 0xffff0000u);
}

// ---------------- weight pack: Wt[c][3][16] uint4 (bf16 pairs) ----------------

__device__ __forceinline__ float wval(const float* Wp, const float* Wf,
                                      int r, int f) {
    if (f < 63)  return Wp[(size_t)r * 63 + f];
    if (f == 63) return Wf[(size_t)r * 64];
    if (f < 127) return Wf[(size_t)r * 64 + (f - 63)];
    return 0.0f;   // dead feature 127
}

__global__ __launch_bounds__(256) void k_pack(const float* __restrict__ Wp,
                                              const float* __restrict__ Wf,
                                              uint4* __restrict__ Wt) {
    const int c   = blockIdx.x * 16 + (threadIdx.x >> 4);
    const int l16 = threadIdx.x & 15;
    #pragma unroll
    for (int j = 0; j < 3; ++j) {
        const int r = 3 * c + j;
        uint4 q;
        q.x = f2bf(wval(Wp, Wf, r, l16))       | (f2bf(wval(Wp, Wf, r, 16 + l16))  << 16);
        q.y = f2bf(wval(Wp, Wf, r, 32 + l16))  | (f2bf(wval(Wp, Wf, r, 48 + l16))  << 16);
        q.z = f2bf(wval(Wp, Wf, r, 64 + l16))  | (f2bf(wval(Wp, Wf, r, 80 + l16))  << 16);
        q.w = f2bf(wval(Wp, Wf, r, 96 + l16))  | (f2bf(wval(Wp, Wf, r, 112 + l16)) << 16);
        Wt[(size_t)(c * 3 + j) * 16 + l16] = q;
    }
}

// dot of 8 x-values against one packed uint4 of 8 bf16 weights
__device__ __forceinline__ float dot8(const uint4& q,
                                      float x0, float x1, float x2, float x3,
                                      float x4, float x5, float x6, float x7) {
    return fmaf(x0, blo(q.x), x1 * bhi(q.x)) + fmaf(x2, blo(q.y), x3 * bhi(q.y))
         + fmaf(x4, blo(q.z), x5 * bhi(q.z)) + fmaf(x6, blo(q.w), x7 * bhi(q.w));
}

// ---------------- main compute (npts % (nW*4) == 0 specialization) --------

__global__ __launch_bounds__(256, 8) void k_main_pipe(
    const float* __restrict__ X,
    const int*   __restrict__ cid,
    const uint4* __restrict__ Wt,    // [256][3][16]
    float*       __restrict__ out,   // [N][3]
    int npts)
{
    const int lane = threadIdx.x & 63;
    const int l16  = lane & 15;
    const int qr   = lane >> 4;                 // quarter id 0..3
    const bool leader = (l16 == 15);
    const int o7   = leader ? 126 : 112 + l16;  // clamp dead feature 127
    const int wid  = (blockIdx.x * blockDim.x + threadIdx.x) >> 6;
    const int nW   = (gridDim.x * blockDim.x) >> 6;
    const int step = nW * 4;                    // points per global iteration
    const int last = npts - 1;
    const int niter = npts / step;              // exact by caller contract

    int p = wid * 4 + qr;

    // ---- prologue: cid + X for iteration 0 ----
    int c = cid[p];
    const float* xr0 = X + (size_t)p * ROWW;
    float x0 = xr0[l16],      x1 = xr0[16 + l16];
    float x2 = xr0[32 + l16], x3 = xr0[48 + l16];
    float x4 = xr0[64 + l16], x5 = xr0[80 + l16];
    float x6 = xr0[96 + l16], x7 = xr0[o7];

    for (int t = 0; t < niter; ++t) {
        // ---- (1) weights for CURRENT point (c resolved one iter ago) ----
        const uint4* wb = Wt + (size_t)c * 48 + l16;
        const uint4 q0 = wb[0];         // j=0, k=0..7 (bf16 pairs)
        const uint4 q1 = wb[16];        // j=1
        const uint4 q2 = wb[32];        // j=2
        __builtin_amdgcn_sched_barrier(0);

        // ---- (2) prefetch NEXT iteration's cid + X ----
        int pn = p + step;
        if (pn > last) pn = last;       // benign duplicate on final prefetch
        const int cn = cid[pn];
        const float* yr = X + (size_t)pn * ROWW;
        const float y0 = yr[l16],      y1 = yr[16 + l16];
        const float y2 = yr[32 + l16], y3 = yr[48 + l16];
        const float y4 = yr[64 + l16], y5 = yr[80 + l16];
        const float y6 = yr[96 + l16], y7 = yr[o7];
        __builtin_amdgcn_sched_barrier(0);

        // ---- (3) compute current (waits only on Wt group) ----
        float a0 = dot8(q0, x0, x1, x2, x3, x4, x5, x6, x7);
        float a1 = dot8(q1, x0, x1, x2, x3, x4, x5, x6, x7);
        float a2 = dot8(q2, x0, x1, x2, x3, x4, x5, x6, x7);

        a0 = row_sum(a0);
        a1 = row_sum(a1);
        a2 = row_sum(a2);

        if (leader) {                   // lanes 15/31/47/63: own quarter's point
            float* o = out + 3 * (size_t)p;
            o[0] = a0; o[1] = a1; o[2] = a2;
        }

        // ---- (4) rotate banks ----
        p += step; c = cn;
        x0 = y0; x1 = y1; x2 = y2; x3 = y3;
        x4 = y4; x5 = y5; x6 = y6; x7 = y7;
    }
}

// ---------------- generic quarter-wave kernel (any npts) ----------------

__global__ __launch_bounds__(256, 8) void k_main(
    const float* __restrict__ X,
    const int*   __restrict__ cid,
    const uint4* __restrict__ Wt,    // [256][3][16]
    float*       __restrict__ out,   // [N][3]
    int npts)
{
    const int lane = threadIdx.x & 63;
    const int l16  = lane & 15;
    const int qr   = lane >> 4;
    const bool leader = (l16 == 15);
    const int o7   = leader ? 126 : 112 + l16;
    const int wid  = (blockIdx.x * blockDim.x + threadIdx.x) >> 6;
    const int nW   = (gridDim.x * blockDim.x) >> 6;
    const int step = nW * 4;
    const int last = npts - 1;
    const int niter = (npts + step - 1) / step;

    int p = wid * 4 + qr;
    int c = cid[min(p, last)];

    for (int t = 0; t < niter; ++t) {
        const int pc = min(p, last);
        const float* xr = X + (size_t)pc * ROWW;
        const float x0 = xr[l16];
        const float x1 = xr[16 + l16];
        const float x2 = xr[32 + l16];
        const float x3 = xr[48 + l16];
        const float x4 = xr[64 + l16];
        const float x5 = xr[80 + l16];
        const float x6 = xr[96 + l16];
        const float x7 = xr[o7];

        const int pn = p + step;
        const int cn = cid[min(pn, last)];

        const uint4* wb = Wt + (size_t)c * 48 + l16;
        const uint4 q0 = wb[0];
        const uint4 q1 = wb[16];
        const uint4 q2 = wb[32];

        float a0 = dot8(q0, x0, x1, x2, x3, x4, x5, x6, x7);
        float a1 = dot8(q1, x0, x1, x2, x3, x4, x5, x6, x7);
        float a2 = dot8(q2, x0, x1, x2, x3, x4, x5, x6, x7);

        a0 = row_sum(a0);
        a1 = row_sum(a1);
        a2 = row_sum(a2);

        if (leader && p < npts) {
            float* o = out + 3 * (size_t)p;
            o[0] = a0; o[1] = a1; o[2] = a2;
        }

        p = pn; c = cn;
    }
}

// ---------------- fallback (ws too small): round-3 direct kernel ----------------

__global__ __launch_bounds__(256, 8) void lad_fallback(
    const float* __restrict__ X, const int* __restrict__ cid,
    const float* __restrict__ Wp, const float* __restrict__ Wf,
    float* __restrict__ out, int npts)
{
    const int lane  = threadIdx.x & 63;
    const int wid   = (blockIdx.x * blockDim.x + threadIdx.x) >> 6;
    const int nW    = (gridDim.x * blockDim.x) >> 6;
    const int lanec = (lane < 63) ? lane : 62;
    const bool l63  = (lane == 63);

    for (int n = wid; n < npts; n += 2 * nW) {
        const int n2 = n + nW;
        const bool has2 = (n2 < npts);

        const float* x0 = X + (size_t)n * ROWW;
        float xa0 = x0[lane];
        float xb0 = x0[63 + lane];
        int   c0  = __builtin_amdgcn_readfirstlane(cid[n]);

        float xa1 = 0.0f, xb1 = 0.0f;
        int   c1  = 0;
        if (has2) {
            const float* x1 = X + (size_t)n2 * ROWW;
            xa1 = x1[lane];
            xb1 = x1[63 + lane];
            c1  = __builtin_amdgcn_readfirstlane(cid[n2]);
        }
        if (l63) { xa0 = 0.0f; xa1 = 0.0f; }

        const float* wp0 = Wp + (size_t)(3 * c0) * 63;
        const float* wf0 = Wf + (size_t)(3 * c0) * 64;
        const float* wp1 = Wp + (size_t)(3 * c1) * 63;
        const float* wf1 = Wf + (size_t)(3 * c1) * 64;

        float a00 = fmaf(xa0, wp0[lanec],       xb0 * wf0[lane]);
        float a01 = fmaf(xa0, wp0[63 + lanec],  xb0 * wf0[64 + lane]);
        float a02 = fmaf(xa0, wp0[126 + lanec], xb0 * wf0[128 + lane]);
        float a10 = fmaf(xa1, wp1[lanec],       xb1 * wf1[lane]);
        float a11 = fmaf(xa1, wp1[63 + lanec],  xb1 * wf1[64 + lane]);
        float a12 = fmaf(xa1, wp1[126 + lanec], xb1 * wf1[128 + lane]);

        a00 = wave_sum63(a00); a01 = wave_sum63(a01); a02 = wave_sum63(a02);
        a10 = wave_sum63(a10); a11 = wave_sum63(a11); a12 = wave_sum63(a12);

        if (l63) {
            float* o0 = out + 3 * (size_t)n;
            o0[0] = a00; o0[1] = a01; o0[2] = a02;
            if (has2) {
                float* o1 = out + 3 * (size_t)n2;
                o1[0] = a10; o1[1] = a11; o1[2] = a12;
            }
        }
    }
}

extern "C" void kernel_launch(void* const* d_in, const int* in_sizes, int n_in,
                              void* d_out, int out_size, void* d_ws, size_t ws_size,
                              hipStream_t stream) {
    const float* X   = (const float*)d_in[0];
    const int*   cid = (const int*)d_in[1];
    const float* Wp  = (const float*)d_in[2];
    const float* Wf  = (const float*)d_in[3];
    float* out = (float*)d_out;
    const int npts = in_sizes[1];   // cluster_ids element count == N

    const size_t wt_bytes = (size_t)NC * 3 * 16 * sizeof(uint4);  // 192 KiB
    if (ws_size < wt_bytes) {
        dim3 grid(2048), block(256);
        hipLaunchKernelGGL(lad_fallback, grid, block, 0, stream,
                           X, cid, Wp, Wf, out, npts);
        return;
    }

    uint4* Wt = (uint4*)d_ws;
    hipLaunchKernelGGL(k_pack, dim3(NC / 16), dim3(256), 0, stream, Wp, Wf, Wt);

    const int nW = (2048 * 256) >> 6;   // 8192 waves
    const int step = nW * 4;
    if (npts % step == 0) {
        hipLaunchKernelGGL(k_main_pipe, dim3(2048), dim3(256), 0, stream,
                           X, cid, Wt, out, npts);
    } else {
        hipLaunchKernelGGL(k_main, dim3(2048), dim3(256), 0, stream,
                           X, cid, Wt, out, npts);
    }
}

// Round 12
// 31.982 us; speedup vs baseline: 1.7280x; 1.0222x over previous
//
#include <hip/hip_runtime.h>

// LinearAutoDecoder: rgb[n, j] = dot(X[n, 0:63],  W_pos[3*cid[n]+j, :]) +
//                                dot(X[n, 63:127], W_feat[3*cid[n]+j, :])
//
// Quarter-wave (16 lanes) per point, 4 points/wave-iteration, 1-iter pipe.
// Lane l16 covers CONTIGUOUS features 8*l16 .. 8*l16+7  ->  X is 2 dwordx4
// loads per lane (each instruction: 4 quarters x 256B contiguous).
// Weights: bf16 table Wt[c][3][16] uint4 (192 KiB in d_ws), feature pairing
// matches the contiguous layout; f==63 -> Wf[r][0], f==127 -> 0 folded in.
// Store: after row_sum, lanes 12..15 of each quarter hold the full sum;
// lanes 12..14 select a0/a1/a2 -> the wave's 12 outputs are contiguous
// (out[12*wid .. +11]) -> ONE exec-masked global_store_dword.
// VMEM per wave-iter: 2 X + 3 Wt + 1 cid + 1 store = 7 (was 33 in r11).

constexpr int ROWW = 127;   // 63 pos + 64 latent
constexpr int NC   = 256;   // clusters

typedef float f32x4v __attribute__((ext_vector_type(4), aligned(4)));

template <int CTRL, int RMASK, int BMASK>
__device__ __forceinline__ float dpp_add(float x) {
    int t = __builtin_amdgcn_update_dpp(0, __builtin_bit_cast(int, x),
                                        CTRL, RMASK, BMASK, false);
    return x + __builtin_bit_cast(float, t);
}

// Sum within each 16-lane row; full sum valid in lanes 12..15 of each row16.
__device__ __forceinline__ float row_sum(float x) {
    x = dpp_add<0xB1,  0xF, 0xF>(x);  // quad_perm xor1
    x = dpp_add<0x4E,  0xF, 0xF>(x);  // quad_perm xor2
    x = dpp_add<0x114, 0xF, 0xE>(x);  // row_shr:4  (banks 1-3)
    x = dpp_add<0x118, 0xF, 0xC>(x);  // row_shr:8  (banks 2-3)
    return x;
}

// Full-wave sum for the fallback kernel; valid in lane 63.
__device__ __forceinline__ float wave_sum63(float x) {
    x = row_sum(x);
    x = dpp_add<0x142, 0xA, 0xF>(x);  // row_bcast:15
    x = dpp_add<0x143, 0xC, 0xF>(x);  // row_bcast:31
    return x;
}

// bf16 helpers
__device__ __forceinline__ unsigned f2bf(float f) {      // RNE
    unsigned u = __builtin_bit_cast(unsigned, f);
    return (u + 0x7fffu + ((u >> 16) & 1u)) >> 16;
}
__device__ __forceinline__ float blo(unsigned u) {
    return __builtin_bit_cast(float, u << 16);
}
__device__ __forceinline__ float bhi(unsigned u) {
    return __builtin_bit_cast(float, u & 0xffff0000u);
}

__device__ __forceinline__ float wval(const float* Wp, const float* Wf,
                                      int r, int f) {
    if (f < 63)  return Wp[(size_t)r * 63 + f];
    if (f == 63) return Wf[(size_t)r * 64];
    if (f < 127) return Wf[(size_t)r * 64 + (f - 63)];
    return 0.0f;   // dead feature 127
}

// ---------------- weight pack: Wt[c][3][16] uint4, contiguous pairing ------

__global__ __launch_bounds__(256) void k_pack(const float* __restrict__ Wp,
                                              const float* __restrict__ Wf,
                                              uint4* __restrict__ Wt) {
    const int c   = blockIdx.x * 16 + (threadIdx.x >> 4);
    const int l16 = threadIdx.x & 15;
    const int f   = 8 * l16;
    #pragma unroll
    for (int j = 0; j < 3; ++j) {
        const int r = 3 * c + j;
        uint4 q;
        q.x = f2bf(wval(Wp, Wf, r, f + 0)) | (f2bf(wval(Wp, Wf, r, f + 1)) << 16);
        q.y = f2bf(wval(Wp, Wf, r, f + 2)) | (f2bf(wval(Wp, Wf, r, f + 3)) << 16);
        q.z = f2bf(wval(Wp, Wf, r, f + 4)) | (f2bf(wval(Wp, Wf, r, f + 5)) << 16);
        q.w = f2bf(wval(Wp, Wf, r, f + 6)) | (f2bf(wval(Wp, Wf, r, f + 7)) << 16);
        Wt[(size_t)(c * 3 + j) * 16 + l16] = q;
    }
}

// dot of 8 x-values against one packed uint4 of 8 bf16 weights
__device__ __forceinline__ float dot8(const uint4& q,
                                      float x0, float x1, float x2, float x3,
                                      float x4, float x5, float x6, float x7) {
    return fmaf(x0, blo(q.x), x1 * bhi(q.x)) + fmaf(x2, blo(q.y), x3 * bhi(q.y))
         + fmaf(x4, blo(q.z), x5 * bhi(q.z)) + fmaf(x6, blo(q.w), x7 * bhi(q.w));
}

// ---------------- main compute (npts % (nW*4) == 0 specialization) --------

__global__ __launch_bounds__(256, 8) void k_main_pipe(
    const float* __restrict__ X,
    const int*   __restrict__ cid,
    const uint4* __restrict__ Wt,    // [256][3][16]
    float*       __restrict__ out,   // [N][3]
    int npts)
{
    const int lane = threadIdx.x & 63;
    const int l16  = lane & 15;
    const int qr   = lane >> 4;                 // quarter id 0..3
    const int wid  = (blockIdx.x * blockDim.x + threadIdx.x) >> 6;
    const int nW   = (gridDim.x * blockDim.x) >> 6;
    const int step = nW * 4;                    // points per global iteration
    const int last = npts - 1;
    const int niter = npts / step;              // exact by caller contract
    const size_t T = (size_t)npts * ROWW;       // X element count

    int p = wid * 4 + qr;

    // ---- prologue: cid + X for iteration 0 ----
    int c = cid[p];
    f32x4v xv1, xv2;  bool badc;
    {
        const size_t e1 = (size_t)p * ROWW + 8 * l16;
        size_t e2 = e1 + 4;
        badc = e2 > T - 4;             // only lane15 @ p == last
        if (badc) e2 = T - 4;
        xv1 = *(const f32x4v*)(X + e1);
        xv2 = *(const f32x4v*)(X + e2);
    }

    for (int t = 0; t < niter; ++t) {
        // ---- (1) weights for CURRENT point (c resolved one iter ago) ----
        const uint4* wb = Wt + (size_t)c * 48 + l16;
        const uint4 q0 = wb[0];
        const uint4 q1 = wb[16];
        const uint4 q2 = wb[32];
        __builtin_amdgcn_sched_barrier(0);

        // ---- (2) prefetch NEXT iteration's cid + X ----
        int pn = p + step;
        if (pn > last) pn = last;      // final-iter prefetch: benign duplicate
        const int cn = cid[pn];
        f32x4v yv1, yv2;  bool badn;
        {
            const size_t e1 = (size_t)pn * ROWW + 8 * l16;
            size_t e2 = e1 + 4;
            badn = e2 > T - 4;
            if (badn) e2 = T - 4;
            yv1 = *(const f32x4v*)(X + e1);
            yv2 = *(const f32x4v*)(X + e2);
        }
        __builtin_amdgcn_sched_barrier(0);

        // ---- (3) compute current (waits only on Wt group) ----
        const float x0 = xv1.x, x1 = xv1.y, x2 = xv1.z, x3 = xv1.w;
        const float x4 = badc ? xv2.y : xv2.x;
        const float x5 = badc ? xv2.z : xv2.y;
        const float x6 = badc ? xv2.w : xv2.z;
        const float x7 = xv2.w;        // dead on lane15 (weight 0)

        float a0 = dot8(q0, x0, x1, x2, x3, x4, x5, x6, x7);
        float a1 = dot8(q1, x0, x1, x2, x3, x4, x5, x6, x7);
        float a2 = dot8(q2, x0, x1, x2, x3, x4, x5, x6, x7);

        a0 = row_sum(a0);
        a1 = row_sum(a1);
        a2 = row_sum(a2);

        // lanes 12..14 of each quarter store {a0,a1,a2} -> 48B contiguous
        const float sv = (l16 == 12) ? a0 : (l16 == 13) ? a1 : a2;
        if (l16 >= 12 && l16 < 15)
            out[3 * (size_t)p + (l16 - 12)] = sv;

        // ---- (4) rotate banks ----
        p = pn; c = cn;
        xv1 = yv1; xv2 = yv2; badc = badn;
    }
}

// ---------------- generic quarter-wave kernel (any npts) ----------------

__global__ __launch_bounds__(256, 8) void k_main(
    const float* __restrict__ X,
    const int*   __restrict__ cid,
    const uint4* __restrict__ Wt,    // [256][3][16]
    float*       __restrict__ out,   // [N][3]
    int npts)
{
    const int lane = threadIdx.x & 63;
    const int l16  = lane & 15;
    const int qr   = lane >> 4;
    const int wid  = (blockIdx.x * blockDim.x + threadIdx.x) >> 6;
    const int nW   = (gridDim.x * blockDim.x) >> 6;
    const int step = nW * 4;
    const int last = npts - 1;
    const int niter = (npts + step - 1) / step;
    const size_t T = (size_t)npts * ROWW;

    int p = wid * 4 + qr;
    int c = cid[min(p, last)];

    for (int t = 0; t < niter; ++t) {
        const int pc = min(p, last);
        const size_t e1 = (size_t)pc * ROWW + 8 * l16;
        size_t e2 = e1 + 4;
        const bool bad = e2 > T - 4;
        if (bad) e2 = T - 4;
        const f32x4v xv1 = *(const f32x4v*)(X + e1);
        const f32x4v xv2 = *(const f32x4v*)(X + e2);

        const int pn = p + step;
        const int cn = cid[min(pn, last)];

        const uint4* wb = Wt + (size_t)c * 48 + l16;
        const uint4 q0 = wb[0];
        const uint4 q1 = wb[16];
        const uint4 q2 = wb[32];

        const float x0 = xv1.x, x1 = xv1.y, x2 = xv1.z, x3 = xv1.w;
        const float x4 = bad ? xv2.y : xv2.x;
        const float x5 = bad ? xv2.z : xv2.y;
        const float x6 = bad ? xv2.w : xv2.z;
        const float x7 = xv2.w;

        float a0 = dot8(q0, x0, x1, x2, x3, x4, x5, x6, x7);
        float a1 = dot8(q1, x0, x1, x2, x3, x4, x5, x6, x7);
        float a2 = dot8(q2, x0, x1, x2, x3, x4, x5, x6, x7);

        a0 = row_sum(a0);
        a1 = row_sum(a1);
        a2 = row_sum(a2);

        const float sv = (l16 == 12) ? a0 : (l16 == 13) ? a1 : a2;
        if (p < npts && l16 >= 12 && l16 < 15)
            out[3 * (size_t)p + (l16 - 12)] = sv;

        p = pn; c = cn;
    }
}

// ---------------- fallback (ws too small): round-3 direct kernel ----------------

__global__ __launch_bounds__(256, 8) void lad_fallback(
    const float* __restrict__ X, const int* __restrict__ cid,
    const float* __restrict__ Wp, const float* __restrict__ Wf,
    float* __restrict__ out, int npts)
{
    const int lane  = threadIdx.x & 63;
    const int wid   = (blockIdx.x * blockDim.x + threadIdx.x) >> 6;
    const int nW    = (gridDim.x * blockDim.x) >> 6;
    const int lanec = (lane < 63) ? lane : 62;
    const bool l63  = (lane == 63);

    for (int n = wid; n < npts; n += 2 * nW) {
        const int n2 = n + nW;
        const bool has2 = (n2 < npts);

        const float* x0 = X + (size_t)n * ROWW;
        float xa0 = x0[lane];
        float xb0 = x0[63 + lane];
        int   c0  = __builtin_amdgcn_readfirstlane(cid[n]);

        float xa1 = 0.0f, xb1 = 0.0f;
        int   c1  = 0;
        if (has2) {
            const float* x1 = X + (size_t)n2 * ROWW;
            xa1 = x1[lane];
            xb1 = x1[63 + lane];
            c1  = __builtin_amdgcn_readfirstlane(cid[n2]);
        }
        if (l63) { xa0 = 0.0f; xa1 = 0.0f; }

        const float* wp0 = Wp + (size_t)(3 * c0) * 63;
        const float* wf0 = Wf + (size_t)(3 * c0) * 64;
        const float* wp1 = Wp + (size_t)(3 * c1) * 63;
        const float* wf1 = Wf + (size_t)(3 * c1) * 64;

        float a00 = fmaf(xa0, wp0[lanec],       xb0 * wf0[lane]);
        float a01 = fmaf(xa0, wp0[63 + lanec],  xb0 * wf0[64 + lane]);
        float a02 = fmaf(xa0, wp0[126 + lanec], xb0 * wf0[128 + lane]);
        float a10 = fmaf(xa1, wp1[lanec],       xb1 * wf1[lane]);
        float a11 = fmaf(xa1, wp1[63 + lanec],  xb1 * wf1[64 + lane]);
        float a12 = fmaf(xa1, wp1[126 + lanec], xb1 * wf1[128 + lane]);

        a00 = wave_sum63(a00); a01 = wave_sum63(a01); a02 = wave_sum63(a02);
        a10 = wave_sum63(a10); a11 = wave_sum63(a11); a12 = wave_sum63(a12);

        if (l63) {
            float* o0 = out + 3 * (size_t)n;
            o0[0] = a00; o0[1] = a01; o0[2] = a02;
            if (has2) {
                float* o1 = out + 3 * (size_t)n2;
                o1[0] = a10; o1[1] = a11; o1[2] = a12;
            }
        }
    }
}

extern "C" void kernel_launch(void* const* d_in, const int* in_sizes, int n_in,
                              void* d_out, int out_size, void* d_ws, size_t ws_size,
                              hipStream_t stream) {
    const float* X   = (const float*)d_in[0];
    const int*   cid = (const int*)d_in[1];
    const float* Wp  = (const float*)d_in[2];
    const float* Wf  = (const float*)d_in[3];
    float* out = (float*)d_out;
    const int npts = in_sizes[1];   // cluster_ids element count == N

    const size_t wt_bytes = (size_t)NC * 3 * 16 * sizeof(uint4);  // 192 KiB
    if (ws_size < wt_bytes) {
        dim3 grid(2048), block(256);
        hipLaunchKernelGGL(lad_fallback, grid, block, 0, stream,
                           X, cid, Wp, Wf, out, npts);
        return;
    }

    uint4* Wt = (uint4*)d_ws;
    hipLaunchKernelGGL(k_pack, dim3(NC / 16), dim3(256), 0, stream, Wp, Wf, Wt);

    const int nW = (2048 * 256) >> 6;   // 8192 waves
    const int step = nW * 4;
    if (npts % step == 0 && npts > step) {
        hipLaunchKernelGGL(k_main_pipe, dim3(2048), dim3(256), 0, stream,
                           X, cid, Wt, out, npts);
    } else {
        hipLaunchKernelGGL(k_main, dim3(2048), dim3(256), 0, stream,
                           X, cid, Wt, out, npts);
    }
}

// Round 13
// 31.487 us; speedup vs baseline: 1.7552x; 1.0157x over previous
//
#include <hip/hip_runtime.h>

// LinearAutoDecoder: rgb[n, j] = dot(X[n, 0:63],  W_pos[3*cid[n]+j, :]) +
//                                dot(X[n, 63:127], W_feat[3*cid[n]+j, :])
//
// Quarter-wave (16 lanes) per point, 4 points/wave-iteration.
// Lane l16 covers CONTIGUOUS features 8*l16..8*l16+7 -> X = 2 dwordx4/lane.
// Weights: bf16 table Wt[c][3][16] uint4 (192 KiB in d_ws), f==63 -> Wf[r][0],
// f==127 -> 0 folded in. Store: lanes 12..14 of each quarter emit {a0,a1,a2}
// -> one exec-masked dword store per wave-iteration.
//
// 2-DEEP pipeline (this round's change): body t issues Wt(t+1) / cid(t+2) /
// X(t+1), then computes iteration t whose Wt AND X were issued one full body
// (~400cy) earlier -- no load in the steady loop has less than a body of
// latency cover. Manual unroll-by-2 with named A/B register banks (no
// dynamic indexing, no rotate movs); sched_barrier(0) fences stop the
// compiler from sinking prefetches back to their uses (r8 failure mode).

constexpr int ROWW = 127;   // 63 pos + 64 latent
constexpr int NC   = 256;   // clusters

typedef float f32x4v __attribute__((ext_vector_type(4), aligned(4)));

template <int CTRL, int RMASK, int BMASK>
__device__ __forceinline__ float dpp_add(float x) {
    int t = __builtin_amdgcn_update_dpp(0, __builtin_bit_cast(int, x),
                                        CTRL, RMASK, BMASK, false);
    return x + __builtin_bit_cast(float, t);
}

// Sum within each 16-lane row; full sum valid in lanes 12..15 of each row16.
__device__ __forceinline__ float row_sum(float x) {
    x = dpp_add<0xB1,  0xF, 0xF>(x);  // quad_perm xor1
    x = dpp_add<0x4E,  0xF, 0xF>(x);  // quad_perm xor2
    x = dpp_add<0x114, 0xF, 0xE>(x);  // row_shr:4  (banks 1-3)
    x = dpp_add<0x118, 0xF, 0xC>(x);  // row_shr:8  (banks 2-3)
    return x;
}

// Full-wave sum for the fallback kernel; valid in lane 63.
__device__ __forceinline__ float wave_sum63(float x) {
    x = row_sum(x);
    x = dpp_add<0x142, 0xA, 0xF>(x);  // row_bcast:15
    x = dpp_add<0x143, 0xC, 0xF>(x);  // row_bcast:31
    return x;
}

// bf16 helpers
__device__ __forceinline__ unsigned f2bf(float f) {      // RNE
    unsigned u = __builtin_bit_cast(unsigned, f);
    return (u + 0x7fffu + ((u >> 16) & 1u)) >> 16;
}
__device__ __forceinline__ float blo(unsigned u) {
    return __builtin_bit_cast(float, u << 16);
}
__device__ __forceinline__ float bhi(unsigned u) {
    return __builtin_bit_cast(float, u & 0xffff0000u);
}

__device__ __forceinline__ float wval(const float* Wp, const float* Wf,
                                      int r, int f) {
    if (f < 63)  return Wp[(size_t)r * 63 + f];
    if (f == 63) return Wf[(size_t)r * 64];
    if (f < 127) return Wf[(size_t)r * 64 + (f - 63)];
    return 0.0f;   // dead feature 127
}

// ---------------- weight pack: Wt[c][3][16] uint4, contiguous pairing ------

__global__ __launch_bounds__(256) void k_pack(const float* __restrict__ Wp,
                                              const float* __restrict__ Wf,
                                              uint4* __restrict__ Wt) {
    const int c   = blockIdx.x * 16 + (threadIdx.x >> 4);
    const int l16 = threadIdx.x & 15;
    const int f   = 8 * l16;
    #pragma unroll
    for (int j = 0; j < 3; ++j) {
        const int r = 3 * c + j;
        uint4 q;
        q.x = f2bf(wval(Wp, Wf, r, f + 0)) | (f2bf(wval(Wp, Wf, r, f + 1)) << 16);
        q.y = f2bf(wval(Wp, Wf, r, f + 2)) | (f2bf(wval(Wp, Wf, r, f + 3)) << 16);
        q.z = f2bf(wval(Wp, Wf, r, f + 4)) | (f2bf(wval(Wp, Wf, r, f + 5)) << 16);
        q.w = f2bf(wval(Wp, Wf, r, f + 6)) | (f2bf(wval(Wp, Wf, r, f + 7)) << 16);
        Wt[(size_t)(c * 3 + j) * 16 + l16] = q;
    }
}

// dot of 8 x-values against one packed uint4 of 8 bf16 weights
__device__ __forceinline__ float dot8(const uint4& q,
                                      float x0, float x1, float x2, float x3,
                                      float x4, float x5, float x6, float x7) {
    return fmaf(x0, blo(q.x), x1 * bhi(q.x)) + fmaf(x2, blo(q.y), x3 * bhi(q.y))
         + fmaf(x4, blo(q.z), x5 * bhi(q.z)) + fmaf(x6, blo(q.w), x7 * bhi(q.w));
}

// compute + store one iteration from a register bank
__device__ __forceinline__ void comp_store(
    const f32x4v& v1, const f32x4v& v2, bool bad,
    const uint4& q0, const uint4& q1, const uint4& q2,
    float* __restrict__ out, int p, int l16)
{
    const float x0 = v1.x, x1 = v1.y, x2 = v1.z, x3 = v1.w;
    const float x4 = bad ? v2.y : v2.x;
    const float x5 = bad ? v2.z : v2.y;
    const float x6 = bad ? v2.w : v2.z;
    const float x7 = v2.w;             // dead on lane15 (weight 0)

    float a0 = dot8(q0, x0, x1, x2, x3, x4, x5, x6, x7);
    float a1 = dot8(q1, x0, x1, x2, x3, x4, x5, x6, x7);
    float a2 = dot8(q2, x0, x1, x2, x3, x4, x5, x6, x7);

    a0 = row_sum(a0);
    a1 = row_sum(a1);
    a2 = row_sum(a2);

    const float sv = (l16 == 12) ? a0 : (l16 == 13) ? a1 : a2;
    if (l16 >= 12 && l16 < 15)
        out[3 * (size_t)p + (l16 - 12)] = sv;
}

// ---------------- main compute: 2-deep pipe, nbody even ----------------

__global__ __launch_bounds__(256, 8) void k_main_pipe2(
    const float* __restrict__ X,
    const int*   __restrict__ cid,
    const uint4* __restrict__ Wt,    // [256][3][16]
    float*       __restrict__ out,   // [N][3]
    int npts)
{
    const int lane = threadIdx.x & 63;
    const int l16  = lane & 15;
    const int qr   = lane >> 4;
    const int wid  = (blockIdx.x * blockDim.x + threadIdx.x) >> 6;
    const int nW   = (gridDim.x * blockDim.x) >> 6;
    const int step = nW * 4;
    const int last = npts - 1;
    const int nbody = npts / step;          // even and >= 2 by caller contract
    const size_t T = (size_t)npts * ROWW;

    int p = wid * 4 + qr;

    // ---- prologue: bank A = iteration 0; c1 = cluster for iteration 1 ----
    f32x4v xa1, xa2;  bool bada;
    {
        const size_t e1 = (size_t)p * ROWW + 8 * l16;
        size_t e2 = e1 + 4;
        bada = e2 > T - 4;
        if (bada) e2 = T - 4;
        xa1 = *(const f32x4v*)(X + e1);
        xa2 = *(const f32x4v*)(X + e2);
    }
    const int cA = cid[p];
    uint4 qa0, qa1, qa2;
    {
        const uint4* wb = Wt + (size_t)cA * 48 + l16;
        qa0 = wb[0]; qa1 = wb[16]; qa2 = wb[32];
    }
    int c1 = cid[min(p + step, last)];

    f32x4v xb1, xb2;  bool badb;
    uint4 qb0, qb1, qb2;

    for (int t = 0; t < nbody; t += 2) {
        // ======== body t: prefetch (t+1) into bank B, compute bank A ========
        {
            const uint4* wb = Wt + (size_t)c1 * 48 + l16;
            qb0 = wb[0]; qb1 = wb[16]; qb2 = wb[32];
        }
        const int c2 = cid[min(p + 2 * step, last)];
        {
            const int pn = min(p + step, last);
            const size_t e1 = (size_t)pn * ROWW + 8 * l16;
            size_t e2 = e1 + 4;
            badb = e2 > T - 4;
            if (badb) e2 = T - 4;
            xb1 = *(const f32x4v*)(X + e1);
            xb2 = *(const f32x4v*)(X + e2);
        }
        __builtin_amdgcn_sched_barrier(0);
        comp_store(xa1, xa2, bada, qa0, qa1, qa2, out, p, l16);

        // ======== body t+1: prefetch (t+2) into bank A, compute bank B ======
        {
            const uint4* wb = Wt + (size_t)c2 * 48 + l16;
            qa0 = wb[0]; qa1 = wb[16]; qa2 = wb[32];
        }
        c1 = cid[min(p + 3 * step, last)];
        {
            const int pn = min(p + 2 * step, last);
            const size_t e1 = (size_t)pn * ROWW + 8 * l16;
            size_t e2 = e1 + 4;
            bada = e2 > T - 4;
            if (bada) e2 = T - 4;
            xa1 = *(const f32x4v*)(X + e1);
            xa2 = *(const f32x4v*)(X + e2);
        }
        __builtin_amdgcn_sched_barrier(0);
        comp_store(xb1, xb2, badb, qb0, qb1, qb2, out, p + step, l16);

        p += 2 * step;
    }
}

// ---------------- generic quarter-wave kernel (any npts) ----------------

__global__ __launch_bounds__(256, 8) void k_main(
    const float* __restrict__ X,
    const int*   __restrict__ cid,
    const uint4* __restrict__ Wt,    // [256][3][16]
    float*       __restrict__ out,   // [N][3]
    int npts)
{
    const int lane = threadIdx.x & 63;
    const int l16  = lane & 15;
    const int qr   = lane >> 4;
    const int wid  = (blockIdx.x * blockDim.x + threadIdx.x) >> 6;
    const int nW   = (gridDim.x * blockDim.x) >> 6;
    const int step = nW * 4;
    const int last = npts - 1;
    const int niter = (npts + step - 1) / step;
    const size_t T = (size_t)npts * ROWW;

    int p = wid * 4 + qr;
    int c = cid[min(p, last)];

    for (int t = 0; t < niter; ++t) {
        const int pc = min(p, last);
        const size_t e1 = (size_t)pc * ROWW + 8 * l16;
        size_t e2 = e1 + 4;
        const bool bad = e2 > T - 4;
        if (bad) e2 = T - 4;
        const f32x4v xv1 = *(const f32x4v*)(X + e1);
        const f32x4v xv2 = *(const f32x4v*)(X + e2);

        const int pn = p + step;
        const int cn = cid[min(pn, last)];

        const uint4* wb = Wt + (size_t)c * 48 + l16;
        const uint4 q0 = wb[0];
        const uint4 q1 = wb[16];
        const uint4 q2 = wb[32];

        if (p < npts)
            comp_store(xv1, xv2, bad, q0, q1, q2, out, p, l16);

        p = pn; c = cn;
    }
}

// ---------------- fallback (ws too small): round-3 direct kernel ----------------

__global__ __launch_bounds__(256, 8) void lad_fallback(
    const float* __restrict__ X, const int* __restrict__ cid,
    const float* __restrict__ Wp, const float* __restrict__ Wf,
    float* __restrict__ out, int npts)
{
    const int lane  = threadIdx.x & 63;
    const int wid   = (blockIdx.x * blockDim.x + threadIdx.x) >> 6;
    const int nW    = (gridDim.x * blockDim.x) >> 6;
    const int lanec = (lane < 63) ? lane : 62;
    const bool l63  = (lane == 63);

    for (int n = wid; n < npts; n += 2 * nW) {
        const int n2 = n + nW;
        const bool has2 = (n2 < npts);

        const float* x0 = X + (size_t)n * ROWW;
        float xa0 = x0[lane];
        float xb0 = x0[63 + lane];
        int   c0  = __builtin_amdgcn_readfirstlane(cid[n]);

        float xa1 = 0.0f, xb1 = 0.0f;
        int   c1  = 0;
        if (has2) {
            const float* x1 = X + (size_t)n2 * ROWW;
            xa1 = x1[lane];
            xb1 = x1[63 + lane];
            c1  = __builtin_amdgcn_readfirstlane(cid[n2]);
        }
        if (l63) { xa0 = 0.0f; xa1 = 0.0f; }

        const float* wp0 = Wp + (size_t)(3 * c0) * 63;
        const float* wf0 = Wf + (size_t)(3 * c0) * 64;
        const float* wp1 = Wp + (size_t)(3 * c1) * 63;
        const float* wf1 = Wf + (size_t)(3 * c1) * 64;

        float a00 = fmaf(xa0, wp0[lanec],       xb0 * wf0[lane]);
        float a01 = fmaf(xa0, wp0[63 + lanec],  xb0 * wf0[64 + lane]);
        float a02 = fmaf(xa0, wp0[126 + lanec], xb0 * wf0[128 + lane]);
        float a10 = fmaf(xa1, wp1[lanec],       xb1 * wf1[lane]);
        float a11 = fmaf(xa1, wp1[63 + lanec],  xb1 * wf1[64 + lane]);
        float a12 = fmaf(xa1, wp1[126 + lanec], xb1 * wf1[128 + lane]);

        a00 = wave_sum63(a00); a01 = wave_sum63(a01); a02 = wave_sum63(a02);
        a10 = wave_sum63(a10); a11 = wave_sum63(a11); a12 = wave_sum63(a12);

        if (l63) {
            float* o0 = out + 3 * (size_t)n;
            o0[0] = a00; o0[1] = a01; o0[2] = a02;
            if (has2) {
                float* o1 = out + 3 * (size_t)n2;
                o1[0] = a10; o1[1] = a11; o1[2] = a12;
            }
        }
    }
}

extern "C" void kernel_launch(void* const* d_in, const int* in_sizes, int n_in,
                              void* d_out, int out_size, void* d_ws, size_t ws_size,
                              hipStream_t stream) {
    const float* X   = (const float*)d_in[0];
    const int*   cid = (const int*)d_in[1];
    const float* Wp  = (const float*)d_in[2];
    const float* Wf  = (const float*)d_in[3];
    float* out = (float*)d_out;
    const int npts = in_sizes[1];   // cluster_ids element count == N

    const size_t wt_bytes = (size_t)NC * 3 * 16 * sizeof(uint4);  // 192 KiB
    if (ws_size < wt_bytes) {
        dim3 grid(2048), block(256);
        hipLaunchKernelGGL(lad_fallback, grid, block, 0, stream,
                           X, cid, Wp, Wf, out, npts);
        return;
    }

    uint4* Wt = (uint4*)d_ws;
    hipLaunchKernelGGL(k_pack, dim3(NC / 16), dim3(256), 0, stream, Wp, Wf, Wt);

    const int nW = (2048 * 256) >> 6;   // 8192 waves
    const int step = nW * 4;
    if (npts % (2 * step) == 0) {
        hipLaunchKernelGGL(k_main_pipe2, dim3(2048), dim3(256), 0, stream,
                           X, cid, Wt, out, npts);
    } else {
        hipLaunchKernelGGL(k_main, dim3(2048), dim3(256), 0, stream,
                           X, cid, Wt, out, npts);
    }
}